// Round 1
// baseline (631.901 us; speedup 1.0000x reference)
//
#include <hip/hip_runtime.h>
#include <hip/hip_bf16.h>

// ---------------------------------------------------------------------------
// DPP helpers: reductions within each 16-lane row (VALU pipe, no LDS traffic)
// ---------------------------------------------------------------------------
template <int CTRL>
__device__ __forceinline__ float dppmov(float v) {
    return __int_as_float(__builtin_amdgcn_update_dpp(
        0, __float_as_int(v), CTRL, 0xF, 0xF, true));
}
// sum across the 16 lanes of a DPP row; result in ALL 16 lanes
__device__ __forceinline__ float grp_sum16(float v) {
    v += dppmov<0xB1>(v);   // quad_perm(1,0,3,2)  == xor 1
    v += dppmov<0x4E>(v);   // quad_perm(2,3,0,1)  == xor 2
    v += dppmov<0x124>(v);  // row_ror:4
    v += dppmov<0x128>(v);  // row_ror:8
    return v;
}
__device__ __forceinline__ float grp_max16(float v) {
    v = fmaxf(v, dppmov<0xB1>(v));
    v = fmaxf(v, dppmov<0x4E>(v));
    v = fmaxf(v, dppmov<0x124>(v));
    v = fmaxf(v, dppmov<0x128>(v));
    return v;
}

// ---------------------------------------------------------------------------
// Generic fp32 tiled GEMM: C[z] = A[:, k0:k0+kc] * B[k0:k0+kc, :] (+bias)
// Tile 64x64, 256 threads, 4x4 accum per thread. Used for QKV proj (z=1)
// and for split-K output GEMM (z=8, partials).
// ---------------------------------------------------------------------------
#define TM 64
#define TN 64
#define TK 16

__global__ __launch_bounds__(256) void gemm_tiled(
    const float* __restrict__ A, int lda,
    const float* __restrict__ B, int ldb,
    float* __restrict__ C, int ldc,
    int M, int N, int kc, const float* __restrict__ bias)
{
    __shared__ float As[TK][TM + 4];
    __shared__ float Bs[TK][TN + 4];
    const int tid = threadIdx.x;
    const int bm = blockIdx.y * TM;
    const int bn = blockIdx.x * TN;
    const int k0 = blockIdx.z * kc;
    C += (size_t)blockIdx.z * M * N;

    const int tx = tid & 15;   // 4 output cols each
    const int ty = tid >> 4;   // 4 output rows each

    float acc[4][4];
#pragma unroll
    for (int i = 0; i < 4; ++i)
#pragma unroll
        for (int j = 0; j < 4; ++j)
            acc[i][j] = bias ? bias[bn + tx * 4 + j] : 0.0f;

    const int ar = tid >> 2;        // A stage: row 0..63
    const int ac = (tid & 3) * 4;   // A stage: k offset 0,4,8,12
    const int br = tid >> 4;        // B stage: k row 0..15
    const int bc = (tid & 15) * 4;  // B stage: col offset

    for (int kt = k0; kt < k0 + kc; kt += TK) {
        float4 a = *(const float4*)&A[(size_t)(bm + ar) * lda + kt + ac];
        float4 b = *(const float4*)&B[(size_t)(kt + br) * ldb + bn + bc];
        As[ac + 0][ar] = a.x; As[ac + 1][ar] = a.y;
        As[ac + 2][ar] = a.z; As[ac + 3][ar] = a.w;
        *(float4*)&Bs[br][bc] = b;
        __syncthreads();
#pragma unroll
        for (int kk = 0; kk < TK; ++kk) {
            float4 a4 = *(const float4*)&As[kk][ty * 4];
            float4 b4 = *(const float4*)&Bs[kk][tx * 4];
            float av[4] = {a4.x, a4.y, a4.z, a4.w};
            float bv[4] = {b4.x, b4.y, b4.z, b4.w};
#pragma unroll
            for (int i = 0; i < 4; ++i)
#pragma unroll
                for (int j = 0; j < 4; ++j)
                    acc[i][j] = fmaf(av[i], bv[j], acc[i][j]);
        }
        __syncthreads();
    }
#pragma unroll
    for (int i = 0; i < 4; ++i) {
        float4 o = make_float4(acc[i][0], acc[i][1], acc[i][2], acc[i][3]);
        *(float4*)&C[(size_t)(bm + ty * 4 + i) * ldc + bn + tx * 4] = o;
    }
}

// ---------------------------------------------------------------------------
// Fused per-token kernel: scores -> alpha-entmax (bisect+Newton) -> P*V^T.
// One token per block (512 blocks, 256 threads). K,V in LDS (fp32, [h][512]).
// Each 16-lane group owns one row: 32 score elems per lane in VGPRs.
// Exponent fast-path for alpha=1.5 (p = relu(t)^2).
// ---------------------------------------------------------------------------
__global__ __launch_bounds__(256) void attn_entmax(
    const float* qg, const float* kg, const float* vg,
    float* resg, const float* __restrict__ alpha_p)
{
    __shared__ float ks[8 * 512];
    __shared__ float vs[8 * 512];
    __shared__ float rs[8 * 512];
    const int t = blockIdx.x;
    const int tid = threadIdx.x;

    const float alpha = alpha_p[0];
    const float expo = 1.0f / (alpha - 1.0f);      // = 2 for alpha=1.5 (exact)
    const bool fast = (expo == 2.0f);
    const float scl = (alpha - 1.0f) * 0.04419417382415922f;  // (a-1)/sqrt(512)
    const float span = 1.0f - powf(1.0f / 512.0f, alpha - 1.0f); // tau_hi-tau_lo

    {   // stage K, V for this token
        const float4* k4 = (const float4*)(kg + (size_t)t * 4096);
        const float4* v4 = (const float4*)(vg + (size_t)t * 4096);
#pragma unroll
        for (int u = 0; u < 4; ++u) {
            int idx = tid + 256 * u;
            ((float4*)ks)[idx] = k4[idx];
            ((float4*)vs)[idx] = v4[idx];
        }
    }
    __syncthreads();

    const int lane = tid & 63;
    const int w = tid >> 6;        // wave 0..3
    const int sub = lane >> 4;     // 16-lane group 0..3 (one row each)
    const int lx = lane & 15;

    const float* qrow = qg + (size_t)t * 4096;

    for (int it = 0; it < 32; ++it) {
        const int i = it * 16 + w * 4 + sub;    // this group's row

        float qv[8];
#pragma unroll
        for (int h = 0; h < 8; ++h) qv[h] = qrow[h * 512 + i];

        // ---- scores: x[j] = (alpha-1)/sqrt(512) * sum_h q[h,i]*k[h,j]
        // lane columns: j = lx*4 + 64*u + {0..3}, u = 0..7 (32 per lane)
        float x[32];
#pragma unroll
        for (int u = 0; u < 8; ++u) {
            float a0 = 0, a1 = 0, a2 = 0, a3 = 0;
#pragma unroll
            for (int h = 0; h < 8; ++h) {
                float4 k4 = *(const float4*)&ks[h * 512 + lx * 4 + 64 * u];
                float qh = qv[h];
                a0 = fmaf(qh, k4.x, a0); a1 = fmaf(qh, k4.y, a1);
                a2 = fmaf(qh, k4.z, a2); a3 = fmaf(qh, k4.w, a3);
            }
            x[4 * u + 0] = a0 * scl; x[4 * u + 1] = a1 * scl;
            x[4 * u + 2] = a2 * scl; x[4 * u + 3] = a3 * scl;
        }

        // ---- row max
        float m = x[0];
#pragma unroll
        for (int j = 1; j < 32; ++j) m = fmaxf(m, x[j]);
        m = grp_max16(m);

        // ---- bracket [max-1, max-(1/d)^(a-1)]; f(tau_lo) >= 1 always
        float tau = m - 1.0f;
        float dm = span;

        // 4 bisection steps (keeps tau on the f>=1 side)
#pragma unroll
        for (int bi = 0; bi < 4; ++bi) {
            dm *= 0.5f;
            float tm = tau + dm;
            float f = 0.0f;
            if (fast) {
#pragma unroll
                for (int j = 0; j < 32; ++j) {
                    float r = fmaxf(x[j] - tm, 0.0f);
                    f = fmaf(r, r, f);
                }
            } else {
#pragma unroll
                for (int j = 0; j < 32; ++j) {
                    float r = fmaxf(x[j] - tm, 0.0f);
                    f += __powf(r, expo);
                }
            }
            f = grp_sum16(f);
            if (f >= 1.0f) tau = tm;   // per-group cndmask, no divergence cost
        }

        // 10 Newton steps: monotone from the left (f convex, decreasing)
#pragma unroll
        for (int ni = 0; ni < 10; ++ni) {
            float f = 0.0f, g = 0.0f;
            if (fast) {
#pragma unroll
                for (int j = 0; j < 32; ++j) {
                    float r = fmaxf(x[j] - tau, 0.0f);
                    f = fmaf(r, r, f); g += r;
                }
            } else {
#pragma unroll
                for (int j = 0; j < 32; ++j) {
                    float r = fmaxf(x[j] - tau, 0.0f);
                    float rp = __powf(r, expo - 1.0f);
                    g += rp; f += rp * r;
                }
            }
            f = grp_sum16(f);
            g = grp_sum16(g);
            float denom = (fast ? 2.0f : expo) * g;
            tau += (f - 1.0f) / fmaxf(denom, 1e-30f);
        }

        // ---- final (unnormalized) p into x; S for normalization
        float S = 0.0f;
        if (fast) {
#pragma unroll
            for (int j = 0; j < 32; ++j) {
                float r = fmaxf(x[j] - tau, 0.0f);
                x[j] = r * r; S += x[j];
            }
        } else {
#pragma unroll
            for (int j = 0; j < 32; ++j) {
                float r = fmaxf(x[j] - tau, 0.0f);
                x[j] = __powf(r, expo); S += x[j];
            }
        }
        S = grp_sum16(S);
        const float invS = 1.0f / S;

        // ---- res[h,i] = invS * sum_j p[j] * v[h,j]
#pragma unroll
        for (int h = 0; h < 8; ++h) {
            float a = 0.0f;
#pragma unroll
            for (int u = 0; u < 8; ++u) {
                float4 v4 = *(const float4*)&vs[h * 512 + lx * 4 + 64 * u];
                a = fmaf(x[4 * u + 0], v4.x, a);
                a = fmaf(x[4 * u + 1], v4.y, a);
                a = fmaf(x[4 * u + 2], v4.z, a);
                a = fmaf(x[4 * u + 3], v4.w, a);
            }
            a = grp_sum16(a) * invS;
            if (lx == h) rs[h * 512 + i] = a;
        }
    }
    __syncthreads();
    {   // coalesced write-out of res (layout [h*512 + i] == reshape(h*e))
        float4* r4 = (float4*)(resg + (size_t)t * 4096);
        const float4* s4 = (const float4*)rs;
#pragma unroll
        for (int u = 0; u < 4; ++u) {
            int idx = tid + 256 * u;
            r4[idx] = s4[idx];
        }
    }
}

// ---------------------------------------------------------------------------
// out[m][n] = bu[n] + sum_s partial[s][m][n]
// ---------------------------------------------------------------------------
__global__ __launch_bounds__(256) void reduce_bias(
    const float* __restrict__ part, const float* __restrict__ bu,
    float* __restrict__ out, int MN, int S)
{
    int i = blockIdx.x * 256 + threadIdx.x;
    if (i >= MN) return;
    float a = bu[i & 511];
#pragma unroll
    for (int s = 0; s < 8; ++s) a += part[(size_t)s * MN + i];
    out[i] = a;
}

// ---------------------------------------------------------------------------
extern "C" void kernel_launch(void* const* d_in, const int* in_sizes, int n_in,
                              void* d_out, int out_size, void* d_ws, size_t ws_size,
                              hipStream_t stream)
{
    const float* x  = (const float*)d_in[0];
    const float* Wq = (const float*)d_in[1];
    const float* bq = (const float*)d_in[2];
    const float* Wk = (const float*)d_in[3];
    const float* bk = (const float*)d_in[4];
    const float* Wv = (const float*)d_in[5];
    const float* bv = (const float*)d_in[6];
    const float* Wu = (const float*)d_in[7];
    const float* bu = (const float*)d_in[8];
    const float* al = (const float*)d_in[9];
    float* out = (float*)d_out;
    float* ws = (float*)d_ws;

    // ws layout (floats): q[2M] | k[2M] | v[2M]  (24 MB total)
    // res aliases q (each attn block reads its q slice before writing res),
    // split-K partials alias k (k is dead after attn_entmax).
    float* q = ws;
    float* k = ws + 2097152;
    float* v = ws + 2 * 2097152;
    float* res = q;
    float* part = k;

    dim3 blk(256);

    // QKV projections: (512x512) @ (512x4096) + bias
    dim3 g1(4096 / TN, 512 / TM, 1);
    gemm_tiled<<<g1, blk, 0, stream>>>(x, 512, Wq, 4096, q, 4096, 512, 4096, 512, bq);
    gemm_tiled<<<g1, blk, 0, stream>>>(x, 512, Wk, 4096, k, 4096, 512, 4096, 512, bk);
    gemm_tiled<<<g1, blk, 0, stream>>>(x, 512, Wv, 4096, v, 4096, 512, 4096, 512, bv);

    // fused scores + alpha-entmax + P*V^T, one token per block
    attn_entmax<<<dim3(512), blk, 0, stream>>>(q, k, v, res, al);

    // out = res @ Wu + bu, split-K=8 into partials then reduce
    dim3 g3(512 / TN, 512 / TM, 8);
    gemm_tiled<<<g3, blk, 0, stream>>>(res, 4096, Wu, 512, part, 512, 512, 512, 512, nullptr);
    reduce_bias<<<dim3(262144 / 256), blk, 0, stream>>>(part, bu, out, 262144, 8);
}

// Round 2
// 412.611 us; speedup vs baseline: 1.5315x; 1.5315x over previous
//
#include <hip/hip_runtime.h>
#include <hip/hip_bf16.h>

// ---------------------------------------------------------------------------
// DPP helpers: reductions within each 16-lane row (VALU pipe, no LDS traffic)
// ---------------------------------------------------------------------------
template <int CTRL>
__device__ __forceinline__ float dppmov(float v) {
    return __int_as_float(__builtin_amdgcn_update_dpp(
        0, __float_as_int(v), CTRL, 0xF, 0xF, true));
}
// sum across the 16 lanes of a DPP row; result in ALL 16 lanes
__device__ __forceinline__ float grp_sum16(float v) {
    v += dppmov<0xB1>(v);   // quad_perm(1,0,3,2)  == xor 1
    v += dppmov<0x4E>(v);   // quad_perm(2,3,0,1)  == xor 2
    v += dppmov<0x124>(v);  // row_ror:4
    v += dppmov<0x128>(v);  // row_ror:8
    return v;
}
__device__ __forceinline__ float grp_max16(float v) {
    v = fmaxf(v, dppmov<0xB1>(v));
    v = fmaxf(v, dppmov<0x4E>(v));
    v = fmaxf(v, dppmov<0x124>(v));
    v = fmaxf(v, dppmov<0x128>(v));
    return v;
}

// ---------------------------------------------------------------------------
// Generic fp32 tiled GEMM: C[z] = A[:, k0:k0+kc] * B[k0:k0+kc, :] (+bias)
// Tile 64x64, 256 threads, 4x4 accum per thread. Used for QKV proj (z=1)
// and for split-K output GEMM (z=8, partials).
// ---------------------------------------------------------------------------
#define TM 64
#define TN 64
#define TK 16

__global__ __launch_bounds__(256) void gemm_tiled(
    const float* __restrict__ A, int lda,
    const float* __restrict__ B, int ldb,
    float* __restrict__ C, int ldc,
    int M, int N, int kc, const float* __restrict__ bias)
{
    __shared__ float As[TK][TM + 4];
    __shared__ float Bs[TK][TN + 4];
    const int tid = threadIdx.x;
    const int bm = blockIdx.y * TM;
    const int bn = blockIdx.x * TN;
    const int k0 = blockIdx.z * kc;
    C += (size_t)blockIdx.z * M * N;

    const int tx = tid & 15;   // 4 output cols each
    const int ty = tid >> 4;   // 4 output rows each

    float acc[4][4];
#pragma unroll
    for (int i = 0; i < 4; ++i)
#pragma unroll
        for (int j = 0; j < 4; ++j)
            acc[i][j] = bias ? bias[bn + tx * 4 + j] : 0.0f;

    const int ar = tid >> 2;        // A stage: row 0..63
    const int ac = (tid & 3) * 4;   // A stage: k offset 0,4,8,12
    const int br = tid >> 4;        // B stage: k row 0..15
    const int bc = (tid & 15) * 4;  // B stage: col offset

    for (int kt = k0; kt < k0 + kc; kt += TK) {
        float4 a = *(const float4*)&A[(size_t)(bm + ar) * lda + kt + ac];
        float4 b = *(const float4*)&B[(size_t)(kt + br) * ldb + bn + bc];
        As[ac + 0][ar] = a.x; As[ac + 1][ar] = a.y;
        As[ac + 2][ar] = a.z; As[ac + 3][ar] = a.w;
        *(float4*)&Bs[br][bc] = b;
        __syncthreads();
#pragma unroll
        for (int kk = 0; kk < TK; ++kk) {
            float4 a4 = *(const float4*)&As[kk][ty * 4];
            float4 b4 = *(const float4*)&Bs[kk][tx * 4];
            float av[4] = {a4.x, a4.y, a4.z, a4.w};
            float bv[4] = {b4.x, b4.y, b4.z, b4.w};
#pragma unroll
            for (int i = 0; i < 4; ++i)
#pragma unroll
                for (int j = 0; j < 4; ++j)
                    acc[i][j] = fmaf(av[i], bv[j], acc[i][j]);
        }
        __syncthreads();
    }
#pragma unroll
    for (int i = 0; i < 4; ++i) {
        float4 o = make_float4(acc[i][0], acc[i][1], acc[i][2], acc[i][3]);
        *(float4*)&C[(size_t)(bm + ty * 4 + i) * ldc + bn + tx * 4] = o;
    }
}

// ---------------------------------------------------------------------------
// Fused per-half-token kernel: scores -> alpha-entmax -> P*V^T.
// Grid 1024: 2 blocks per token, 256 rows each (16 row-iterations).
// K,V (full 8x512) + q (8x256) staged in LDS = 40 KB -> 3-4 blocks/CU.
// Each 16-lane group owns one row: 32 score elems per lane in VGPRs.
// alpha=1.5 fast path: p = relu(t)^2; tau via 3 bisections + 6 Newton steps
// (monotone from the left; quadratic once support stabilizes; final
// normalization absorbs residual tau error, matching ensure_sum_one=True).
// ---------------------------------------------------------------------------
#define NBISECT 3
#define NNEWTON 6

__global__ __launch_bounds__(256, 3) void attn_entmax(
    const float* qg, const float* kg, const float* vg,
    float* resg, const float* __restrict__ alpha_p)
{
    __shared__ float ks[8 * 512];
    __shared__ float vs[8 * 512];
    __shared__ float qs[8 * 256];
    const int t = blockIdx.x >> 1;
    const int base = (blockIdx.x & 1) << 8;    // row half: 0 or 256
    const int tid = threadIdx.x;

    const float alpha = alpha_p[0];
    const float expo = 1.0f / (alpha - 1.0f);      // = 2 for alpha=1.5 (exact)
    const bool fast = (expo == 2.0f);
    const float scl = (alpha - 1.0f) * 0.04419417382415922f;  // (a-1)/sqrt(512)
    const float span = 1.0f - powf(1.0f / 512.0f, alpha - 1.0f); // tau_hi-tau_lo

    {   // stage K, V (full token) and q (this block's 256 rows)
        const float4* k4 = (const float4*)(kg + (size_t)t * 4096);
        const float4* v4 = (const float4*)(vg + (size_t)t * 4096);
#pragma unroll
        for (int u = 0; u < 4; ++u) {
            int idx = tid + 256 * u;
            ((float4*)ks)[idx] = k4[idx];
            ((float4*)vs)[idx] = v4[idx];
        }
        const float4* q4 = (const float4*)(qg + (size_t)t * 4096);
#pragma unroll
        for (int u = 0; u < 2; ++u) {
            int idx = tid + 256 * u;               // = h*64 + j4
            ((float4*)qs)[idx] = q4[(idx >> 6) * 128 + (base >> 2) + (idx & 63)];
        }
    }
    __syncthreads();

    const int lane = tid & 63;
    const int w = tid >> 6;        // wave 0..3
    const int sub = lane >> 4;     // 16-lane group 0..3 (one row each)
    const int lx = lane & 15;

    for (int it = 0; it < 16; ++it) {
        const int il = it * 16 + w * 4 + sub;   // local row 0..255

        float qv[8];
#pragma unroll
        for (int h = 0; h < 8; ++h) qv[h] = qs[h * 256 + il];

        // ---- scores: x[j] = (alpha-1)/sqrt(512) * sum_h q[h,i]*k[h,j]
        // lane columns: j = lx*4 + 64*u + {0..3}, u = 0..7 (32 per lane)
        float x[32];
#pragma unroll 2
        for (int u = 0; u < 8; ++u) {
            float a0 = 0, a1 = 0, a2 = 0, a3 = 0;
#pragma unroll
            for (int h = 0; h < 8; ++h) {
                float4 k4 = *(const float4*)&ks[h * 512 + lx * 4 + 64 * u];
                float qh = qv[h];
                a0 = fmaf(qh, k4.x, a0); a1 = fmaf(qh, k4.y, a1);
                a2 = fmaf(qh, k4.z, a2); a3 = fmaf(qh, k4.w, a3);
            }
            x[4 * u + 0] = a0 * scl; x[4 * u + 1] = a1 * scl;
            x[4 * u + 2] = a2 * scl; x[4 * u + 3] = a3 * scl;
        }

        // ---- row max
        float m = x[0];
#pragma unroll
        for (int j = 1; j < 32; ++j) m = fmaxf(m, x[j]);
        m = grp_max16(m);

        // ---- bracket [max-1, max-(1/d)^(a-1)]; f(tau_lo) >= 1 always
        float tau = m - 1.0f;
        float dm = span;

#pragma unroll
        for (int bi = 0; bi < NBISECT; ++bi) {
            dm *= 0.5f;
            float tm = tau + dm;
            float f = 0.0f;
            if (fast) {
#pragma unroll
                for (int j = 0; j < 32; ++j) {
                    float r = fmaxf(x[j] - tm, 0.0f);
                    f = fmaf(r, r, f);
                }
            } else {
#pragma unroll
                for (int j = 0; j < 32; ++j) {
                    float r = fmaxf(x[j] - tm, 0.0f);
                    f += __powf(r, expo);
                }
            }
            f = grp_sum16(f);
            if (f >= 1.0f) tau = tm;   // per-group cndmask
        }

        // Newton: monotone from the left (f convex, decreasing)
#pragma unroll
        for (int ni = 0; ni < NNEWTON; ++ni) {
            float f = 0.0f, g = 0.0f;
            if (fast) {
#pragma unroll
                for (int j = 0; j < 32; ++j) {
                    float r = fmaxf(x[j] - tau, 0.0f);
                    f = fmaf(r, r, f); g += r;
                }
            } else {
#pragma unroll
                for (int j = 0; j < 32; ++j) {
                    float r = fmaxf(x[j] - tau, 0.0f);
                    float rp = __powf(r, expo - 1.0f);
                    g += rp; f += rp * r;
                }
            }
            f = grp_sum16(f);
            g = grp_sum16(g);
            float denom = (fast ? 2.0f : expo) * g;
            tau += (f - 1.0f) / fmaxf(denom, 1e-30f);
        }

        // ---- final (unnormalized) p into x; S for normalization
        float S = 0.0f;
        if (fast) {
#pragma unroll
            for (int j = 0; j < 32; ++j) {
                float r = fmaxf(x[j] - tau, 0.0f);
                x[j] = r * r; S += x[j];
            }
        } else {
#pragma unroll
            for (int j = 0; j < 32; ++j) {
                float r = fmaxf(x[j] - tau, 0.0f);
                x[j] = __powf(r, expo); S += x[j];
            }
        }
        S = grp_sum16(S);
        const float invS = 1.0f / S;

        // ---- res[h,i] = invS * sum_j p[j] * v[h,j]; direct exec-masked store
#pragma unroll
        for (int h = 0; h < 8; ++h) {
            float a = 0.0f;
#pragma unroll 2
            for (int u = 0; u < 8; ++u) {
                float4 v4 = *(const float4*)&vs[h * 512 + lx * 4 + 64 * u];
                a = fmaf(x[4 * u + 0], v4.x, a);
                a = fmaf(x[4 * u + 1], v4.y, a);
                a = fmaf(x[4 * u + 2], v4.z, a);
                a = fmaf(x[4 * u + 3], v4.w, a);
            }
            a = grp_sum16(a) * invS;
            if (lx == h) resg[(size_t)t * 4096 + h * 512 + base + il] = a;
        }
    }
}

// ---------------------------------------------------------------------------
// out[m][n] = bu[n] + sum_s partial[s][m][n]
// ---------------------------------------------------------------------------
__global__ __launch_bounds__(256) void reduce_bias(
    const float* __restrict__ part, const float* __restrict__ bu,
    float* __restrict__ out, int MN, int S)
{
    int i = blockIdx.x * 256 + threadIdx.x;
    if (i >= MN) return;
    float a = bu[i & 511];
#pragma unroll
    for (int s = 0; s < 8; ++s) a += part[(size_t)s * MN + i];
    out[i] = a;
}

// ---------------------------------------------------------------------------
extern "C" void kernel_launch(void* const* d_in, const int* in_sizes, int n_in,
                              void* d_out, int out_size, void* d_ws, size_t ws_size,
                              hipStream_t stream)
{
    const float* x  = (const float*)d_in[0];
    const float* Wq = (const float*)d_in[1];
    const float* bq = (const float*)d_in[2];
    const float* Wk = (const float*)d_in[3];
    const float* bk = (const float*)d_in[4];
    const float* Wv = (const float*)d_in[5];
    const float* bv = (const float*)d_in[6];
    const float* Wu = (const float*)d_in[7];
    const float* bu = (const float*)d_in[8];
    const float* al = (const float*)d_in[9];
    float* out = (float*)d_out;
    float* ws = (float*)d_ws;

    // ws layout (floats): q[2M] | k[2M] | v[2M]  (24 MB total)
    // res aliases q (each attn block reads only its own q slice, then writes
    // the same slice), split-K partials alias k (k dead after attn_entmax).
    float* q = ws;
    float* k = ws + 2097152;
    float* v = ws + 2 * 2097152;
    float* res = q;
    float* part = k;

    dim3 blk(256);

    // QKV projections: (512x512) @ (512x4096) + bias
    dim3 g1(4096 / TN, 512 / TM, 1);
    gemm_tiled<<<g1, blk, 0, stream>>>(x, 512, Wq, 4096, q, 4096, 512, 4096, 512, bq);
    gemm_tiled<<<g1, blk, 0, stream>>>(x, 512, Wk, 4096, k, 4096, 512, 4096, 512, bk);
    gemm_tiled<<<g1, blk, 0, stream>>>(x, 512, Wv, 4096, v, 4096, 512, 4096, 512, bv);

    // fused scores + alpha-entmax + P*V^T, half token per block
    attn_entmax<<<dim3(1024), blk, 0, stream>>>(q, k, v, res, al);

    // out = res @ Wu + bu, split-K=8 into partials then reduce
    dim3 g3(512 / TN, 512 / TM, 8);
    gemm_tiled<<<g3, blk, 0, stream>>>(res, 4096, Wu, 512, part, 512, 512, 512, 512, nullptr);
    reduce_bias<<<dim3(262144 / 256), blk, 0, stream>>>(part, bu, out, 262144, 8);
}